// Round 7
// baseline (39915.439 us; speedup 1.0000x reference)
//
#include <hip/hip_runtime.h>
#include <math.h>

// LSTM B=128,T=1024,D=64,H=256,C=6 — xg-precompute + single-CU-per-batch,
// weights in NAMED registers (R7).
//
// R4/R5/R6 failure signature: per-thread weight ARRAYS -> runtime-indexed ->
// scratch (rule: runtime-indexed arrays go to local memory), VGPR stuck at
// 64/128, FETCH ~1 GB of spill traffic, VALUBusy 3-13%. Fix:
//   * 192 individually-NAMED const f16x2 weight scalars via macro repetition
//     (no arrays, every access token-pasted, nothing indexable at runtime)
//   * amdgpu_flat_work_group_size(512,512) + amdgpu_waves_per_eu(2,2)
//     -> arch-VGPR cap 256 (512-reg pool / 2 waves per SIMD)
//   * Wh K-tail (k=192..255) in LDS, transposed [32][1024] f16x2 rows ->
//     lane-consecutive 4B addresses, conflict-free ds_read_b32
// Stage 1 (xg_gemm): xg = x@Wx + bias -> f16 in d_ws (256 MB). Unchanged (R6).
// Stage 2 (lstm_xg): 128 blocks x 512 thr, 1 block/batch, no cross-block sync
//   (R3/R5: device-scope handshake ~6 us/step). Thread owns cols (tid,tid+512)
//   = {i,g} (tid<256) or {f,o}; f,o published via LDS; 2 barriers/step;
//   Wout projection fused on waves 0..5.

#define Tt 1024
#define Dd 64
#define Hh 256
#define G4 1024
#define Cc 6
#define BT (128 * 1024)
#define XG_BYTES ((size_t)BT * G4 * 2)   // 256 MB f16

typedef _Float16 f16x2 __attribute__((ext_vector_type(2)));

__device__ __forceinline__ float dot2(f16x2 a, f16x2 b, float c) {
#if __has_builtin(__builtin_amdgcn_fdot2)
    return __builtin_amdgcn_fdot2(a, b, c, false);
#else
    return c + (float)a.x * (float)b.x + (float)a.y * (float)b.y;
#endif
}
__device__ __forceinline__ float sigm(float p) { return 1.0f / (1.0f + __expf(-p)); }
__device__ __forceinline__ float tanh_fast(float p) {
    return 1.0f - 2.0f / (__expf(2.0f * p) + 1.0f);
}
__device__ __forceinline__ unsigned short f2h(float v) {
    _Float16 h = (_Float16)v;
    return __builtin_bit_cast(unsigned short, h);
}
__device__ __forceinline__ float h2f(unsigned short u) {
    return (float)__builtin_bit_cast(_Float16, u);
}
__device__ __forceinline__ f16x2 bcf(float v) { return __builtin_bit_cast(f16x2, v); }

// ---------------- stage 1: xg = x @ Wx + bias, f16 (verified in R6) --------
__global__ __launch_bounds__(256) void xg_gemm(
    const float* __restrict__ x, const float* __restrict__ Wx,
    const float* __restrict__ bias, unsigned short* __restrict__ xg)
{
    __shared__ float xs[32][65];
    __shared__ float wsl[64][256];

    const int tid = threadIdx.x;
    const long r0 = (long)blockIdx.x * 32;
    const int  c0 = blockIdx.y * 256;

    {
        const float4* src = (const float4*)(x + r0 * Dd);
        float4 v0 = src[tid], v1 = src[tid + 256];
        int e = tid * 4;
        xs[e >> 6][e & 63] = v0.x; xs[e >> 6][(e & 63) + 1] = v0.y;
        xs[e >> 6][(e & 63) + 2] = v0.z; xs[e >> 6][(e & 63) + 3] = v0.w;
        e += 1024;
        xs[e >> 6][e & 63] = v1.x; xs[e >> 6][(e & 63) + 1] = v1.y;
        xs[e >> 6][(e & 63) + 2] = v1.z; xs[e >> 6][(e & 63) + 3] = v1.w;
    }
    for (int i = tid; i < 64 * 64; i += 256) {
        int d = i >> 6, cq = i & 63;
        *(float4*)&wsl[d][cq * 4] = *(const float4*)(Wx + (long)d * G4 + c0 + cq * 4);
    }
    __syncthreads();

    const int r = tid & 31, cg = tid >> 5;
    float acc[32];
    #pragma unroll
    for (int c = 0; c < 32; ++c) acc[c] = bias[c0 + cg * 32 + c];
    for (int k = 0; k < 64; ++k) {
        float xv = xs[r][k];
        #pragma unroll
        for (int c = 0; c < 32; ++c) acc[c] += xv * wsl[k][cg * 32 + c];
    }
    unsigned int ow[16];
    #pragma unroll
    for (int c2 = 0; c2 < 16; ++c2)
        ow[c2] = (unsigned int)f2h(acc[2 * c2]) | ((unsigned int)f2h(acc[2 * c2 + 1]) << 16);
    uint4* dst = (uint4*)(xg + (r0 + r) * G4 + c0 + cg * 32);
    dst[0] = make_uint4(ow[0], ow[1], ow[2], ow[3]);
    dst[1] = make_uint4(ow[4], ow[5], ow[6], ow[7]);
    dst[2] = make_uint4(ow[8], ow[9], ow[10], ow[11]);
    dst[3] = make_uint4(ow[12], ow[13], ow[14], ow[15]);
}

// ---------------- stage 2: recurrence -------------------------------------
// 192 named weight regs: pair index i covers k = 2i, 2i+1  (i = 0..95)
#define WLOAD(i) \
    const f16x2 w0_##i = f16x2{(_Float16)Wh[(2*(i))*G4 + col0], (_Float16)Wh[(2*(i)+1)*G4 + col0]}; \
    const f16x2 w1_##i = f16x2{(_Float16)Wh[(2*(i))*G4 + col1], (_Float16)Wh[(2*(i)+1)*G4 + col1]};

#define REP96(M) \
  M(0) M(1) M(2) M(3) M(4) M(5) M(6) M(7) \
  M(8) M(9) M(10) M(11) M(12) M(13) M(14) M(15) \
  M(16) M(17) M(18) M(19) M(20) M(21) M(22) M(23) \
  M(24) M(25) M(26) M(27) M(28) M(29) M(30) M(31) \
  M(32) M(33) M(34) M(35) M(36) M(37) M(38) M(39) \
  M(40) M(41) M(42) M(43) M(44) M(45) M(46) M(47) \
  M(48) M(49) M(50) M(51) M(52) M(53) M(54) M(55) \
  M(56) M(57) M(58) M(59) M(60) M(61) M(62) M(63) \
  M(64) M(65) M(66) M(67) M(68) M(69) M(70) M(71) \
  M(72) M(73) M(74) M(75) M(76) M(77) M(78) M(79) \
  M(80) M(81) M(82) M(83) M(84) M(85) M(86) M(87) \
  M(88) M(89) M(90) M(91) M(92) M(93) M(94) M(95)

#define DOT2X(i, hh) { f16x2 h_ = (hh); a0 = dot2(h_, w0_##i, a0); a1 = dot2(h_, w1_##i, a1); }

// one group: two float4 h-chunks (8 f16x2) against pairs i0..i7
#define DOTG(gA, gB, i0,i1,i2,i3,i4,i5,i6,i7) { \
    float4 hA = hvf4[gA]; float4 hB = hvf4[gB]; \
    DOT2X(i0, bcf(hA.x)) DOT2X(i1, bcf(hA.y)) DOT2X(i2, bcf(hA.z)) DOT2X(i3, bcf(hA.w)) \
    DOT2X(i4, bcf(hB.x)) DOT2X(i5, bcf(hB.y)) DOT2X(i6, bcf(hB.z)) DOT2X(i7, bcf(hB.w)) }

__global__ __attribute__((amdgpu_flat_work_group_size(512, 512),
                          amdgpu_waves_per_eu(2, 2)))
void lstm_xg(
    const unsigned short* __restrict__ xg,  // [B,T,1024] f16, bias folded
    const float* __restrict__ Wh,           // [H,4H]
    const float* __restrict__ Wout,         // [H,C]
    const float* __restrict__ bout,         // [C]
    float* __restrict__ out)                // [B,T,C]
{
    __shared__ alignas(16) unsigned short h_f16[Hh];  // current h, f16
    __shared__ float gl[2][Hh];                       // f,o from hi threads
    __shared__ float wout_t[Cc][Hh];
    __shared__ float bout_l[8];
    __shared__ f16x2 wl[32][G4];   // Wh k=192..255: row j = pair(192+2j), 128 KB

    const int tid  = threadIdx.x;
    const int b    = blockIdx.x;
    const int col0 = tid;          // i (tid<256) or f
    const int col1 = tid + 512;    // g (tid<256) or o
    const bool lo  = tid < 256;    // wave-uniform

    // ---- prologue ----
    REP96(WLOAD)                   // 192 named f16x2 weight registers

    #pragma unroll
    for (int j = 0; j < 32; ++j) { // LDS tail, transposed: conflict-free reads
        wl[j][col0] = f16x2{(_Float16)Wh[(192 + 2*j)*G4 + col0],
                            (_Float16)Wh[(193 + 2*j)*G4 + col0]};
        wl[j][col1] = f16x2{(_Float16)Wh[(192 + 2*j)*G4 + col1],
                            (_Float16)Wh[(193 + 2*j)*G4 + col1]};
    }
    if (tid < Hh) h_f16[tid] = 0;
    for (int i = tid; i < Cc * Hh; i += 512) wout_t[i % Cc][i / Cc] = Wout[i];
    if (tid < Cc) bout_l[tid] = bout[tid];

    const unsigned short* xgB = xg + (long)b * Tt * G4;
    unsigned short xgv0 = xgB[col0], xgv1 = xgB[col1];  // t = 0
    float c_state = 0.0f;
    __syncthreads();

    const float4* hvf4 = (const float4*)h_f16;   // broadcast LDS reads
    const f16x2*  hv   = (const f16x2*)h_f16;

    // ---- time loop ----
    for (int t = 0; t < Tt; ++t) {
        // prefetch next xg early (HBM/L2 latency hides under the dots)
        unsigned short nxg0 = 0, nxg1 = 0;
        if (t + 1 < Tt) {
            nxg0 = xgB[(long)(t + 1) * G4 + col0];
            nxg1 = xgB[(long)(t + 1) * G4 + col1];
        }

        float a0 = 0.0f, a1 = 0.0f;
        // k = 0..191 from named registers (12 groups x 8 pairs)
        DOTG(0, 1,   0, 1, 2, 3, 4, 5, 6, 7)
        DOTG(2, 3,   8, 9,10,11,12,13,14,15)
        DOTG(4, 5,  16,17,18,19,20,21,22,23)
        DOTG(6, 7,  24,25,26,27,28,29,30,31)
        DOTG(8, 9,  32,33,34,35,36,37,38,39)
        DOTG(10,11, 40,41,42,43,44,45,46,47)
        DOTG(12,13, 48,49,50,51,52,53,54,55)
        DOTG(14,15, 56,57,58,59,60,61,62,63)
        DOTG(16,17, 64,65,66,67,68,69,70,71)
        DOTG(18,19, 72,73,74,75,76,77,78,79)
        DOTG(20,21, 80,81,82,83,84,85,86,87)
        DOTG(22,23, 88,89,90,91,92,93,94,95)
        // k = 192..255 from LDS (weights runtime-indexed in LDS = fine)
        #pragma unroll
        for (int j = 0; j < 32; ++j) {
            f16x2 h2 = hv[96 + j];
            a0 = dot2(h2, wl[j][col0], a0);
            a1 = dot2(h2, wl[j][col1], a1);
        }

        float pre0 = h2f(xgv0) + a0;
        float pre1 = h2f(xgv1) + a1;
        float r0a, r1a;
        if (lo) { r0a = sigm(pre0); r1a = tanh_fast(pre1); }  // i, g
        else    { r0a = sigm(pre0); r1a = sigm(pre1); }       // f, o

        const int u = tid & 255;
        if (!lo) { gl[0][u] = r0a; gl[1][u] = r1a; }
        __syncthreads();  // B1: gates ready; all h reads of step t done

        if (lo) {
            float fv = gl[0][u], ov = gl[1][u];
            c_state = fv * c_state + r0a * r1a;   // f*c + i*g
            float hval = ov * tanh_fast(c_state);
            h_f16[u] = f2h(hval);
        }
        __syncthreads();  // B2: h(t) staged

        // fused output projection (waves 0..5); overlaps next step's dots
        const int w = tid >> 6, l = tid & 63;
        if (w < Cc) {
            float p = 0.0f;
            #pragma unroll
            for (int j = 0; j < 4; ++j)
                p += h2f(h_f16[l + 64 * j]) * wout_t[w][l + 64 * j];
            #pragma unroll
            for (int off = 32; off > 0; off >>= 1) p += __shfl_down(p, off);
            if (l == 0) out[((long)b * Tt + t) * Cc + w] = p + bout_l[w];
        }

        xgv0 = nxg0; xgv1 = nxg1;
    }
}

// ---------------- fallback: R2 single-block kernel (no ws needed) ----------
__global__ __launch_bounds__(1024) void lstm_fused(
    const float* __restrict__ x, const float* __restrict__ Wx,
    const float* __restrict__ Wh, const float* __restrict__ bias,
    const float* __restrict__ Wout, const float* __restrict__ bout,
    float* __restrict__ out)
{
    __shared__ float h_lds[Hh];
    __shared__ float gates_lds[G4];
    __shared__ float x_lds[2][Dd];
    __shared__ float wout_t[Cc][Hh];
    __shared__ float bout_l[Cc];
    const int tid = threadIdx.x;
    const int b   = blockIdx.x;
    float wx[Dd];
    #pragma unroll
    for (int d = 0; d < Dd; ++d) wx[d] = Wx[d * G4 + tid];
    const float bj = bias[tid];
    if (tid < Hh) h_lds[tid] = 0.0f;
    for (int i = tid; i < Cc * Hh; i += 1024) wout_t[i % Cc][i / Cc] = Wout[i];
    if (tid < Cc) bout_l[tid] = bout[tid];
    const float* xB = x + (long)b * Tt * Dd;
    if (tid < Dd) x_lds[0][tid] = xB[tid];
    float c_state = 0.0f;
    __syncthreads();
    const float* WhB = Wh + tid;
    for (int t = 0; t < Tt; ++t) {
        float gg = bj;
        const float* xr = x_lds[t & 1];
        #pragma unroll
        for (int d = 0; d < Dd; ++d) gg += xr[d] * wx[d];
        #pragma unroll 8
        for (int k = 0; k < Hh; ++k) gg += h_lds[k] * WhB[k * G4];
        float a;
        if (tid < 2 * Hh)      a = 1.0f / (1.0f + expf(-gg));
        else if (tid < 3 * Hh) a = tanhf(gg);
        else                   a = 1.0f / (1.0f + expf(-gg));
        gates_lds[tid] = a;
        __syncthreads();
        if (tid < Hh) {
            float iv = gates_lds[tid], fv = gates_lds[tid + Hh];
            float gv = gates_lds[tid + 2 * Hh], ov = gates_lds[tid + 3 * Hh];
            c_state = fv * c_state + iv * gv;
            h_lds[tid] = ov * tanhf(c_state);
        } else if (tid >= 384 && tid < 448) {
            int tn = t + 1;
            if (tn < Tt) x_lds[tn & 1][tid - 384] = xB[(long)tn * Dd + (tid - 384)];
        }
        __syncthreads();
        const int w = tid >> 6, l = tid & 63;
        if (w < Cc) {
            float p = 0.0f;
            #pragma unroll
            for (int qq = 0; qq < 4; ++qq) p += h_lds[l + 64 * qq] * wout_t[w][l + 64 * qq];
            #pragma unroll
            for (int off = 32; off > 0; off >>= 1) p += __shfl_down(p, off);
            if (l == 0) out[((long)b * Tt + t) * Cc + w] = p + bout_l[w];
        }
    }
}

extern "C" void kernel_launch(void* const* d_in, const int* in_sizes, int n_in,
                              void* d_out, int out_size, void* d_ws, size_t ws_size,
                              hipStream_t stream) {
    const float* x    = (const float*)d_in[0];
    const float* Wx   = (const float*)d_in[1];
    const float* Wh   = (const float*)d_in[2];
    const float* bvec = (const float*)d_in[3];
    const float* Wout = (const float*)d_in[4];
    const float* bout = (const float*)d_in[5];
    float* outp = (float*)d_out;

    if (ws_size >= XG_BYTES) {
        unsigned short* xgws = (unsigned short*)d_ws;
        xg_gemm<<<dim3(BT / 32, 4), dim3(256), 0, stream>>>(x, Wx, bvec, xgws);
        lstm_xg<<<dim3(128), dim3(512), 0, stream>>>(xgws, Wh, Wout, bout, outp);
    } else {
        lstm_fused<<<dim3(128), dim3(1024), 0, stream>>>(x, Wx, Wh, bvec, Wout, bout, outp);
    }
}

// Round 8
// 5586.465 us; speedup vs baseline: 7.1450x; 7.1450x over previous
//
#include <hip/hip_runtime.h>
#include <math.h>

// LSTM B=128,T=1024,D=64,H=256,C=6 — R8: 256-thread blocks, 1 wave/SIMD,
// full 512-VGPR budget, thread owns ALL 4 gates of one unit.
//
// R4-R7 post-mortems: any block >=512 threads gets a hard 128-VGPR allocation
// from LLVM (2+ waves/SIMD must fit the pool) -> weights spill to scratch
// (FETCH 1-14 GB, VALUBusy <14%). Fix: 256-thr block = 1 wave/SIMD -> cap 512.
//   * thread tid = unit u: cols {tid, tid+256, tid+512, tid+768} = {i,f,g,o}
//     -> no gate exchange, no divergence, c_state in-register
//   * Wh k=0..191: 384 NAMED f16x2 registers (macro-generated, zero indexing)
//   * Wh k=192..255: LDS [32][1024] f16x2, lane-consecutive b32, conflict-free
//   * h (256 f16) in LDS, broadcast float4 reads
//   * xg = x@Wx+bias precomputed f16 in d_ws (stage 1, verified R6/R7)
//   * output projection fused: 4 waves x classes {w} + {4+w for w<2}
// 2 barriers/step, no cross-block traffic, 128 blocks (1 batch each).

#define Tt 1024
#define Dd 64
#define Hh 256
#define G4 1024
#define Cc 6
#define BT (128 * 1024)
#define XG_BYTES ((size_t)BT * G4 * 2)   // 256 MB f16

typedef _Float16 f16x2 __attribute__((ext_vector_type(2)));

__device__ __forceinline__ float dot2(f16x2 a, f16x2 b, float c) {
#if __has_builtin(__builtin_amdgcn_fdot2)
    return __builtin_amdgcn_fdot2(a, b, c, false);
#else
    return c + (float)a.x * (float)b.x + (float)a.y * (float)b.y;
#endif
}
__device__ __forceinline__ float sigm(float p) { return 1.0f / (1.0f + __expf(-p)); }
__device__ __forceinline__ float tanh_fast(float p) {
    return 1.0f - 2.0f / (__expf(2.0f * p) + 1.0f);
}
__device__ __forceinline__ unsigned short f2h(float v) {
    _Float16 h = (_Float16)v;
    return __builtin_bit_cast(unsigned short, h);
}
__device__ __forceinline__ float h2f(unsigned short u) {
    return (float)__builtin_bit_cast(_Float16, u);
}
__device__ __forceinline__ f16x2 bcf(float v) { return __builtin_bit_cast(f16x2, v); }

// ---------------- stage 1: xg = x @ Wx + bias, f16 (verified R6/R7) --------
__global__ __launch_bounds__(256) void xg_gemm(
    const float* __restrict__ x, const float* __restrict__ Wx,
    const float* __restrict__ bias, unsigned short* __restrict__ xg)
{
    __shared__ float xs[32][65];
    __shared__ float wsl[64][256];

    const int tid = threadIdx.x;
    const long r0 = (long)blockIdx.x * 32;
    const int  c0 = blockIdx.y * 256;

    {
        const float4* src = (const float4*)(x + r0 * Dd);
        float4 v0 = src[tid], v1 = src[tid + 256];
        int e = tid * 4;
        xs[e >> 6][e & 63] = v0.x; xs[e >> 6][(e & 63) + 1] = v0.y;
        xs[e >> 6][(e & 63) + 2] = v0.z; xs[e >> 6][(e & 63) + 3] = v0.w;
        e += 1024;
        xs[e >> 6][e & 63] = v1.x; xs[e >> 6][(e & 63) + 1] = v1.y;
        xs[e >> 6][(e & 63) + 2] = v1.z; xs[e >> 6][(e & 63) + 3] = v1.w;
    }
    for (int i = tid; i < 64 * 64; i += 256) {
        int d = i >> 6, cq = i & 63;
        *(float4*)&wsl[d][cq * 4] = *(const float4*)(Wx + (long)d * G4 + c0 + cq * 4);
    }
    __syncthreads();

    const int r = tid & 31, cg = tid >> 5;
    float acc[32];
    #pragma unroll
    for (int c = 0; c < 32; ++c) acc[c] = bias[c0 + cg * 32 + c];
    for (int k = 0; k < 64; ++k) {
        float xv = xs[r][k];
        #pragma unroll
        for (int c = 0; c < 32; ++c) acc[c] += xv * wsl[k][cg * 32 + c];
    }
    unsigned int ow[16];
    #pragma unroll
    for (int c2 = 0; c2 < 16; ++c2)
        ow[c2] = (unsigned int)f2h(acc[2 * c2]) | ((unsigned int)f2h(acc[2 * c2 + 1]) << 16);
    uint4* dst = (uint4*)(xg + (r0 + r) * G4 + c0 + cg * 32);
    dst[0] = make_uint4(ow[0], ow[1], ow[2], ow[3]);
    dst[1] = make_uint4(ow[4], ow[5], ow[6], ow[7]);
    dst[2] = make_uint4(ow[8], ow[9], ow[10], ow[11]);
    dst[3] = make_uint4(ow[12], ow[13], ow[14], ow[15]);
}

// ---------------- stage 2: recurrence -------------------------------------
// pair index i covers k = 2i, 2i+1 (i = 0..95); cols A,B,C,D = gates i,f,g,o
#define WLOAD4(i) \
  const f16x2 wA_##i = f16x2{(_Float16)Wh[(2*(i))*G4 + colA], (_Float16)Wh[(2*(i)+1)*G4 + colA]}; \
  const f16x2 wB_##i = f16x2{(_Float16)Wh[(2*(i))*G4 + colB], (_Float16)Wh[(2*(i)+1)*G4 + colB]}; \
  const f16x2 wC_##i = f16x2{(_Float16)Wh[(2*(i))*G4 + colC], (_Float16)Wh[(2*(i)+1)*G4 + colC]}; \
  const f16x2 wD_##i = f16x2{(_Float16)Wh[(2*(i))*G4 + colD], (_Float16)Wh[(2*(i)+1)*G4 + colD]};

#define REP96(M) \
  M(0) M(1) M(2) M(3) M(4) M(5) M(6) M(7) \
  M(8) M(9) M(10) M(11) M(12) M(13) M(14) M(15) \
  M(16) M(17) M(18) M(19) M(20) M(21) M(22) M(23) \
  M(24) M(25) M(26) M(27) M(28) M(29) M(30) M(31) \
  M(32) M(33) M(34) M(35) M(36) M(37) M(38) M(39) \
  M(40) M(41) M(42) M(43) M(44) M(45) M(46) M(47) \
  M(48) M(49) M(50) M(51) M(52) M(53) M(54) M(55) \
  M(56) M(57) M(58) M(59) M(60) M(61) M(62) M(63) \
  M(64) M(65) M(66) M(67) M(68) M(69) M(70) M(71) \
  M(72) M(73) M(74) M(75) M(76) M(77) M(78) M(79) \
  M(80) M(81) M(82) M(83) M(84) M(85) M(86) M(87) \
  M(88) M(89) M(90) M(91) M(92) M(93) M(94) M(95)

#define DOTP(i, hh) { f16x2 h_ = (hh); \
    aA = dot2(h_, wA_##i, aA); aB = dot2(h_, wB_##i, aB); \
    aC = dot2(h_, wC_##i, aC); aD = dot2(h_, wD_##i, aD); }

#define DOTG4(g, i0,i1,i2,i3) { float4 hC_ = hvf4[g]; \
    DOTP(i0, bcf(hC_.x)) DOTP(i1, bcf(hC_.y)) \
    DOTP(i2, bcf(hC_.z)) DOTP(i3, bcf(hC_.w)) }

__global__ __launch_bounds__(256, 1) void lstm_xg(
    const unsigned short* __restrict__ xg,  // [B,T,1024] f16, bias folded
    const float* __restrict__ Wh,           // [H,4H]
    const float* __restrict__ Wout,         // [H,C]
    const float* __restrict__ bout,         // [C]
    float* __restrict__ out)                // [B,T,C]
{
    __shared__ alignas(16) unsigned short h_f16[Hh];  // current h
    __shared__ f16x2 wl[32][G4];                      // Wh k=192..255, 128 KB
    __shared__ float wout_t[Cc][Hh];
    __shared__ float bout_l[8];

    const int tid  = threadIdx.x;
    const int b    = blockIdx.x;
    const int colA = tid;          // gate i of unit tid
    const int colB = tid + 256;    // f
    const int colC = tid + 512;    // g
    const int colD = tid + 768;    // o

    // ---- prologue: 384 named weight registers + LDS tail ----
    REP96(WLOAD4)

    #pragma unroll
    for (int j = 0; j < 32; ++j) {
        wl[j][colA] = f16x2{(_Float16)Wh[(192 + 2*j)*G4 + colA],
                            (_Float16)Wh[(193 + 2*j)*G4 + colA]};
        wl[j][colB] = f16x2{(_Float16)Wh[(192 + 2*j)*G4 + colB],
                            (_Float16)Wh[(193 + 2*j)*G4 + colB]};
        wl[j][colC] = f16x2{(_Float16)Wh[(192 + 2*j)*G4 + colC],
                            (_Float16)Wh[(193 + 2*j)*G4 + colC]};
        wl[j][colD] = f16x2{(_Float16)Wh[(192 + 2*j)*G4 + colD],
                            (_Float16)Wh[(193 + 2*j)*G4 + colD]};
    }
    h_f16[tid] = 0;
    for (int i = tid; i < Cc * Hh; i += 256) wout_t[i % Cc][i / Cc] = Wout[i];
    if (tid < Cc) bout_l[tid] = bout[tid];

    const unsigned short* xgB = xg + (long)b * Tt * G4;
    unsigned short xgA = xgB[colA], xgBv = xgB[colB];
    unsigned short xgC = xgB[colC], xgD = xgB[colD];
    float c_state = 0.0f;
    __syncthreads();

    const float4* hvf4 = (const float4*)h_f16;   // broadcast LDS reads
    const f16x2*  hv   = (const f16x2*)h_f16;

    // ---- time loop ----
    for (int t = 0; t < Tt; ++t) {
        // prefetch next xg (4 coalesced u16 loads; latency hides under dots)
        unsigned short nA = 0, nB = 0, nC = 0, nD = 0;
        if (t + 1 < Tt) {
            const unsigned short* xn = xgB + (long)(t + 1) * G4;
            nA = xn[colA]; nB = xn[colB]; nC = xn[colC]; nD = xn[colD];
        }

        float aA = 0.f, aB = 0.f, aC = 0.f, aD = 0.f;
        // k = 0..191 from named registers (24 groups x 4 pairs)
        DOTG4(0,   0, 1, 2, 3)   DOTG4(1,   4, 5, 6, 7)
        DOTG4(2,   8, 9,10,11)   DOTG4(3,  12,13,14,15)
        DOTG4(4,  16,17,18,19)   DOTG4(5,  20,21,22,23)
        DOTG4(6,  24,25,26,27)   DOTG4(7,  28,29,30,31)
        DOTG4(8,  32,33,34,35)   DOTG4(9,  36,37,38,39)
        DOTG4(10, 40,41,42,43)   DOTG4(11, 44,45,46,47)
        DOTG4(12, 48,49,50,51)   DOTG4(13, 52,53,54,55)
        DOTG4(14, 56,57,58,59)   DOTG4(15, 60,61,62,63)
        DOTG4(16, 64,65,66,67)   DOTG4(17, 68,69,70,71)
        DOTG4(18, 72,73,74,75)   DOTG4(19, 76,77,78,79)
        DOTG4(20, 80,81,82,83)   DOTG4(21, 84,85,86,87)
        DOTG4(22, 88,89,90,91)   DOTG4(23, 92,93,94,95)
        // k = 192..255 from LDS (static j after unroll; lane-consecutive b32)
        #pragma unroll
        for (int j = 0; j < 32; ++j) {
            f16x2 h2 = hv[96 + j];
            aA = dot2(h2, wl[j][colA], aA);
            aB = dot2(h2, wl[j][colB], aB);
            aC = dot2(h2, wl[j][colC], aC);
            aD = dot2(h2, wl[j][colD], aD);
        }

        float ig = sigm(h2f(xgA) + aA);
        float fg = sigm(h2f(xgBv) + aB);
        float gg = tanh_fast(h2f(xgC) + aC);
        float og = sigm(h2f(xgD) + aD);
        c_state = fg * c_state + ig * gg;
        float hval = og * tanh_fast(c_state);

        __syncthreads();  // B1: every thread done reading h(t-1)
        h_f16[tid] = f2h(hval);
        __syncthreads();  // B2: h(t) staged

        // fused output projection: wave w -> class w; waves 0,1 also 4,5
        const int w = tid >> 6, l = tid & 63;
        {
            float p = 0.0f;
            #pragma unroll
            for (int j = 0; j < 4; ++j)
                p += h2f(h_f16[l + 64 * j]) * wout_t[w][l + 64 * j];
            #pragma unroll
            for (int off = 32; off > 0; off >>= 1) p += __shfl_down(p, off);
            if (l == 0) out[((long)b * Tt + t) * Cc + w] = p + bout_l[w];
        }
        if (w < 2) {
            const int c2 = 4 + w;
            float p = 0.0f;
            #pragma unroll
            for (int j = 0; j < 4; ++j)
                p += h2f(h_f16[l + 64 * j]) * wout_t[c2][l + 64 * j];
            #pragma unroll
            for (int off = 32; off > 0; off >>= 1) p += __shfl_down(p, off);
            if (l == 0) out[((long)b * Tt + t) * Cc + c2] = p + bout_l[c2];
        }

        xgA = nA; xgBv = nB; xgC = nC; xgD = nD;
    }
}

// ---------------- fallback: R2 single-block kernel (no ws needed) ----------
__global__ __launch_bounds__(1024) void lstm_fused(
    const float* __restrict__ x, const float* __restrict__ Wx,
    const float* __restrict__ Wh, const float* __restrict__ bias,
    const float* __restrict__ Wout, const float* __restrict__ bout,
    float* __restrict__ out)
{
    __shared__ float h_lds[Hh];
    __shared__ float gates_lds[G4];
    __shared__ float x_lds[2][Dd];
    __shared__ float wout_t[Cc][Hh];
    __shared__ float bout_l[Cc];
    const int tid = threadIdx.x;
    const int b   = blockIdx.x;
    float wx[Dd];
    #pragma unroll
    for (int d = 0; d < Dd; ++d) wx[d] = Wx[d * G4 + tid];
    const float bj = bias[tid];
    if (tid < Hh) h_lds[tid] = 0.0f;
    for (int i = tid; i < Cc * Hh; i += 1024) wout_t[i % Cc][i / Cc] = Wout[i];
    if (tid < Cc) bout_l[tid] = bout[tid];
    const float* xB = x + (long)b * Tt * Dd;
    if (tid < Dd) x_lds[0][tid] = xB[tid];
    float c_state = 0.0f;
    __syncthreads();
    const float* WhB = Wh + tid;
    for (int t = 0; t < Tt; ++t) {
        float gg = bj;
        const float* xr = x_lds[t & 1];
        #pragma unroll
        for (int d = 0; d < Dd; ++d) gg += xr[d] * wx[d];
        #pragma unroll 8
        for (int k = 0; k < Hh; ++k) gg += h_lds[k] * WhB[k * G4];
        float a;
        if (tid < 2 * Hh)      a = 1.0f / (1.0f + expf(-gg));
        else if (tid < 3 * Hh) a = tanhf(gg);
        else                   a = 1.0f / (1.0f + expf(-gg));
        gates_lds[tid] = a;
        __syncthreads();
        if (tid < Hh) {
            float iv = gates_lds[tid], fv = gates_lds[tid + Hh];
            float gv = gates_lds[tid + 2 * Hh], ov = gates_lds[tid + 3 * Hh];
            c_state = fv * c_state + iv * gv;
            h_lds[tid] = ov * tanhf(c_state);
        } else if (tid >= 384 && tid < 448) {
            int tn = t + 1;
            if (tn < Tt) x_lds[tn & 1][tid - 384] = xB[(long)tn * Dd + (tid - 384)];
        }
        __syncthreads();
        const int w = tid >> 6, l = tid & 63;
        if (w < Cc) {
            float p = 0.0f;
            #pragma unroll
            for (int qq = 0; qq < 4; ++qq) p += h_lds[l + 64 * qq] * wout_t[w][l + 64 * qq];
            #pragma unroll
            for (int off = 32; off > 0; off >>= 1) p += __shfl_down(p, off);
            if (l == 0) out[((long)b * Tt + t) * Cc + w] = p + bout_l[w];
        }
    }
}

extern "C" void kernel_launch(void* const* d_in, const int* in_sizes, int n_in,
                              void* d_out, int out_size, void* d_ws, size_t ws_size,
                              hipStream_t stream) {
    const float* x    = (const float*)d_in[0];
    const float* Wx   = (const float*)d_in[1];
    const float* Wh   = (const float*)d_in[2];
    const float* bvec = (const float*)d_in[3];
    const float* Wout = (const float*)d_in[4];
    const float* bout = (const float*)d_in[5];
    float* outp = (float*)d_out;

    if (ws_size >= XG_BYTES) {
        unsigned short* xgws = (unsigned short*)d_ws;
        xg_gemm<<<dim3(BT / 32, 4), dim3(256), 0, stream>>>(x, Wx, bvec, xgws);
        lstm_xg<<<dim3(128), dim3(256), 0, stream>>>(xgws, Wh, Wout, bout, outp);
    } else {
        lstm_fused<<<dim3(128), dim3(1024), 0, stream>>>(x, Wx, Wh, bvec, Wout, bout, outp);
    }
}